// Round 3
// baseline (550.977 us; speedup 1.0000x reference)
//
#include <hip/hip_runtime.h>
#include <math.h>

// Problem constants (validated against in_sizes at launch):
//   E = 1,000,000 edges, R = 1000 relations, D = 200, N_TOTAL = 100,000
#define DD   200
#define DD3  600

// ---------------- zero int counters ----------------
__global__ void zero_kernel(int* __restrict__ cnt, int R) {
    for (int i = threadIdx.x; i < R; i += blockDim.x) cnt[i] = 0;
}

// ---------------- zero float buffer (grid-stride) ----------------
__global__ void zerof_kernel(float* __restrict__ p, int n) {
    int stride = gridDim.x * blockDim.x;
    for (int i = blockIdx.x * blockDim.x + threadIdx.x; i < n; i += stride) p[i] = 0.f;
}

// ---------------- histogram of edge_type ----------------
__global__ void hist_kernel(const int* __restrict__ etype, int* __restrict__ cnt,
                            int E, int R) {
    __shared__ int lc[1024];
    for (int i = threadIdx.x; i < R; i += blockDim.x) lc[i] = 0;
    __syncthreads();
    int stride = gridDim.x * blockDim.x;
    for (int i = blockIdx.x * blockDim.x + threadIdx.x; i < E; i += stride)
        atomicAdd(&lc[etype[i]], 1);
    __syncthreads();
    for (int i = threadIdx.x; i < R; i += blockDim.x)
        if (lc[i]) atomicAdd(&cnt[i], lc[i]);
}

// ---------------- exclusive scan (single block, R <= 1024) ----------------
__global__ void scan_kernel(const int* __restrict__ cnt, int* __restrict__ offs,
                            int* __restrict__ cursor, int R) {
    __shared__ int s[1024];
    int tid = threadIdx.x;
    s[tid] = (tid < R) ? cnt[tid] : 0;
    for (int off = 1; off < 1024; off <<= 1) {
        __syncthreads();
        int v = (tid >= off) ? s[tid - off] : 0;
        __syncthreads();
        s[tid] += v;
    }
    __syncthreads();
    if (tid < R) {
        int excl = (tid == 0) ? 0 : s[tid - 1];
        offs[tid]   = excl;
        cursor[tid] = excl;
        if (tid == R - 1) offs[R] = s[tid];
    }
}

// ---------------- scatter edge ids into relation buckets ----------------
__global__ void scatter_kernel(const int* __restrict__ etype, int* __restrict__ cursor,
                               int* __restrict__ bucket, int E) {
    int stride = gridDim.x * blockDim.x;
    for (int i = blockIdx.x * blockDim.x + threadIdx.x; i < E; i += stride) {
        int r = etype[i];
        int pos = atomicAdd(&cursor[r], 1);
        bucket[pos] = i;
    }
}

// ---------------- transpose W (rows x cols) -> WT (cols x rows) ----------------
__global__ void transpose_kernel(const float* __restrict__ W, float* __restrict__ WT,
                                 int rows, int cols) {
    int idx = blockIdx.x * blockDim.x + threadIdx.x;
    if (idx < rows * cols) {
        int j = idx / cols, d = idx % cols;
        WT[d * rows + j] = W[idx];
    }
}

// ---------------- main: per-(relation, side) mean-gather + GRU ----------------
__launch_bounds__(256)
__global__ void relgru_kernel(const int* __restrict__ eidx,      // (2,E)
                              const int* __restrict__ node_id,   // (N_BATCH)
                              const float* __restrict__ emb,     // (N_TOTAL, D)
                              const float* __restrict__ dyn,     // (R,1,D,2)
                              const float* __restrict__ WT_ih,   // (D, 3D) transposed
                              const float* __restrict__ WT_hh,   // (D, 3D) transposed
                              const float* __restrict__ b_ih,    // (3D)
                              const float* __restrict__ b_hh,    // (3D)
                              const int* __restrict__ offs,      // (R+1)
                              const int* __restrict__ bucket,    // (E)
                              float* __restrict__ out,           // (R,1,D,2)
                              int E) {
    const int r    = blockIdx.x;
    const int side = blockIdx.y;
    const int tid  = threadIdx.x;

    __shared__ float xs[DD];
    __shared__ float hs[DD];
    __shared__ float gi[DD3];
    __shared__ float gh[DD3];
    __shared__ int   nids[256];

    const int beg = offs[r];
    const int end = offs[r + 1];
    const int n   = end - beg;

    // ---- phase A: sum over this relation's edges (thread tid owns dim tid) ----
    float acc = 0.f;
    const float* embd = emb + tid;   // dereferenced only when tid < DD
    for (int base = beg; base < end; base += 256) {
        int m = min(256, end - base);
        if (tid < m) {
            int e = bucket[base + tid];
            nids[tid] = node_id[eidx[(long)side * E + e]];
        }
        __syncthreads();
        if (tid < DD) {
            int i = 0;
            for (; i + 4 <= m; i += 4) {
                int n0 = __builtin_amdgcn_readfirstlane(nids[i]);
                int n1 = __builtin_amdgcn_readfirstlane(nids[i + 1]);
                int n2 = __builtin_amdgcn_readfirstlane(nids[i + 2]);
                int n3 = __builtin_amdgcn_readfirstlane(nids[i + 3]);
                float v0 = embd[(long)n0 * DD];
                float v1 = embd[(long)n1 * DD];
                float v2 = embd[(long)n2 * DD];
                float v3 = embd[(long)n3 * DD];
                acc += (v0 + v1) + (v2 + v3);
            }
            for (; i < m; ++i) {
                int n0 = __builtin_amdgcn_readfirstlane(nids[i]);
                acc += embd[(long)n0 * DD];
            }
        }
        __syncthreads();
    }

    if (tid < DD) {
        xs[tid] = (n > 0) ? acc / (float)n : 0.f;
        hs[tid] = dyn[((long)r * DD + tid) * 2 + side];
    }
    __syncthreads();

    // ---- phase B: two GEMVs (gi = x @ W_ih^T + b_ih ; gh = h @ W_hh^T + b_hh) ----
    {
        float a0 = 0.f, a1 = 0.f, a2 = 0.f;
        float c0 = 0.f, c1 = 0.f, c2 = 0.f;
        const bool has2 = (tid + 512) < DD3;   // tid < 88
        for (int k = 0; k < DD; ++k) {
            float xv = xs[k];
            float hv = hs[k];
            const float* rI = WT_ih + k * DD3;
            const float* rH = WT_hh + k * DD3;
            a0 = fmaf(xv, rI[tid], a0);
            c0 = fmaf(hv, rH[tid], c0);
            a1 = fmaf(xv, rI[tid + 256], a1);
            c1 = fmaf(hv, rH[tid + 256], c1);
            if (has2) {
                a2 = fmaf(xv, rI[tid + 512], a2);
                c2 = fmaf(hv, rH[tid + 512], c2);
            }
        }
        gi[tid]       = a0 + b_ih[tid];
        gh[tid]       = c0 + b_hh[tid];
        gi[tid + 256] = a1 + b_ih[tid + 256];
        gh[tid + 256] = c1 + b_hh[tid + 256];
        if (has2) {
            gi[tid + 512] = a2 + b_ih[tid + 512];
            gh[tid + 512] = c2 + b_hh[tid + 512];
        }
    }
    __syncthreads();

    // ---- phase C: GRU combine + write ----
    if (tid < DD) {
        float rr = 1.f / (1.f + __expf(-(gi[tid] + gh[tid])));
        float zz = 1.f / (1.f + __expf(-(gi[DD + tid] + gh[DD + tid])));
        float nn = tanhf(gi[2 * DD + tid] + rr * gh[2 * DD + tid]);
        float o  = (1.f - zz) * nn + zz * hs[tid];
        out[((long)r * DD + tid) * 2 + side] = o;
    }
}

// ================= fallback path (tiny workspace): atomics into d_out =========

__global__ void atomic_acc_kernel(const int* __restrict__ eidx,
                                  const int* __restrict__ etype,
                                  const int* __restrict__ node_id,
                                  const float* __restrict__ emb,
                                  float* __restrict__ acc,   // (R,D,2), pre-zeroed
                                  int E) {
    int gtid   = blockIdx.x * blockDim.x + threadIdx.x;
    int wave   = gtid >> 6;
    int lane   = gtid & 63;
    int nwaves = (gridDim.x * blockDim.x) >> 6;
    for (int e = wave; e < E; e += nwaves) {
        int r = etype[e];
        float* dst = acc + (long)r * DD * 2;
        for (int side = 0; side < 2; ++side) {
            int nid = node_id[eidx[(long)side * E + e]];
            const float* row = emb + (long)nid * DD;
            for (int d = lane; d < DD; d += 64)
                atomicAdd(&dst[d * 2 + side], row[d]);
        }
    }
}

__launch_bounds__(256)
__global__ void gru_inplace_kernel(const float* __restrict__ dyn,
                                   const float* __restrict__ W_ih,  // (3D, D) row-major
                                   const float* __restrict__ W_hh,
                                   const float* __restrict__ b_ih,
                                   const float* __restrict__ b_hh,
                                   const int* __restrict__ cnt,     // (R)
                                   float* __restrict__ out) {       // (R,D,2) sums in, result out
    const int r    = blockIdx.x;
    const int side = blockIdx.y;
    const int tid  = threadIdx.x;

    __shared__ float xs[DD];
    __shared__ float hs[DD];
    __shared__ float gi[DD3];
    __shared__ float gh[DD3];

    if (tid < DD) {
        float s = out[((long)r * DD + tid) * 2 + side];
        int   n = cnt[r];
        xs[tid] = (n > 0) ? s / (float)n : 0.f;
        hs[tid] = dyn[((long)r * DD + tid) * 2 + side];
    }
    __syncthreads();

    for (int j = tid; j < DD3; j += 256) {
        float a = b_ih[j], c = b_hh[j];
        const float* rI = W_ih + (long)j * DD;
        const float* rH = W_hh + (long)j * DD;
        for (int k = 0; k < DD; ++k) {
            a = fmaf(xs[k], rI[k], a);
            c = fmaf(hs[k], rH[k], c);
        }
        gi[j] = a; gh[j] = c;
    }
    __syncthreads();

    if (tid < DD) {
        float rr = 1.f / (1.f + __expf(-(gi[tid] + gh[tid])));
        float zz = 1.f / (1.f + __expf(-(gi[DD + tid] + gh[DD + tid])));
        float nn = tanhf(gi[2 * DD + tid] + rr * gh[2 * DD + tid]);
        float o  = (1.f - zz) * nn + zz * hs[tid];
        out[((long)r * DD + tid) * 2 + side] = o;
    }
}

extern "C" void kernel_launch(void* const* d_in, const int* in_sizes, int n_in,
                              void* d_out, int out_size, void* d_ws, size_t ws_size,
                              hipStream_t stream) {
    const int*   eidx    = (const int*)d_in[0];
    const int*   etype   = (const int*)d_in[1];
    const int*   node_id = (const int*)d_in[2];
    const float* emb     = (const float*)d_in[3];
    const float* dyn     = (const float*)d_in[4];
    const float* W_ih    = (const float*)d_in[5];
    const float* W_hh    = (const float*)d_in[6];
    const float* b_ih    = (const float*)d_in[7];
    const float* b_hh    = (const float*)d_in[8];
    float*       out     = (float*)d_out;

    const int E  = in_sizes[1];
    const int D  = in_sizes[7] / 3;            // 200
    const int R  = in_sizes[4] / (2 * D);      // 1000
    const int D3 = 3 * D;                      // 600

    // workspace layout (256B aligned chunks)
    char* p = (char*)d_ws;
    auto take = [&](size_t bytes) { char* q = p; p += (bytes + 255) & ~(size_t)255; return q; };
    int*   cnt    = (int*)  take((size_t)R * 4);
    int*   cursor = (int*)  take((size_t)R * 4);
    int*   offs   = (int*)  take((size_t)(R + 1) * 4);
    int*   bucket = (int*)  take((size_t)E * 4);
    float* WT_ih  = (float*)take((size_t)D3 * D * 4);
    float* WT_hh  = (float*)take((size_t)D3 * D * 4);
    size_t needed = (size_t)(p - (char*)d_ws);

    if (ws_size >= needed) {
        // -------- fast path: counting sort by relation, zero hot-loop atomics --------
        zero_kernel<<<1, 256, 0, stream>>>(cnt, R);
        hist_kernel<<<512, 256, 0, stream>>>(etype, cnt, E, R);
        scan_kernel<<<1, 1024, 0, stream>>>(cnt, offs, cursor, R);
        scatter_kernel<<<1024, 256, 0, stream>>>(etype, cursor, bucket, E);
        int tw = (D3 * D + 255) / 256;
        transpose_kernel<<<tw, 256, 0, stream>>>(W_ih, WT_ih, D3, D);
        transpose_kernel<<<tw, 256, 0, stream>>>(W_hh, WT_hh, D3, D);
        dim3 grid(R, 2);
        relgru_kernel<<<grid, 256, 0, stream>>>(eidx, node_id, emb, dyn,
                                                WT_ih, WT_hh, b_ih, b_hh,
                                                offs, bucket, out, E);
    } else {
        // -------- fallback: tiny workspace (R ints), atomics into d_out --------
        zero_kernel<<<1, 256, 0, stream>>>(cnt, R);
        hist_kernel<<<512, 256, 0, stream>>>(etype, cnt, E, R);
        zerof_kernel<<<(R * D * 2 + 255) / 256, 256, 0, stream>>>(out, R * D * 2);
        atomic_acc_kernel<<<2048, 256, 0, stream>>>(eidx, etype, node_id, emb, out, E);
        dim3 grid(R, 2);
        gru_inplace_kernel<<<grid, 256, 0, stream>>>(dyn, W_ih, W_hh, b_ih, b_hh,
                                                     cnt, out);
    }
}

// Round 4
// 452.119 us; speedup vs baseline: 1.2187x; 1.2187x over previous
//
#include <hip/hip_runtime.h>
#include <math.h>

// Problem constants: E=1,000,000  R=1000  D=200  N_BATCH=50,000  N_TOTAL=100,000
#define DD   200
#define DD3  600

static __device__ inline float bf2f(unsigned short u) {
    union { unsigned int i; float f; } x; x.i = ((unsigned int)u) << 16; return x.f;
}
static __device__ inline unsigned short f2bf(float f) {
    union { float f; unsigned int i; } x; x.f = f;
    return (unsigned short)((x.i + 0x7FFFu + ((x.i >> 16) & 1u)) >> 16);
}

// ---------------- zero int counters ----------------
__global__ void zero_kernel(int* __restrict__ cnt, int R) {
    for (int i = threadIdx.x; i < R; i += blockDim.x) cnt[i] = 0;
}

// ---------------- zero float buffer ----------------
__global__ void zerof_kernel(float* __restrict__ p, int n) {
    int stride = gridDim.x * blockDim.x;
    for (int i = blockIdx.x * blockDim.x + threadIdx.x; i < n; i += stride) p[i] = 0.f;
}

// ---------------- histogram of edge_type ----------------
__global__ void hist_kernel(const int* __restrict__ etype, int* __restrict__ cnt,
                            int E, int R) {
    __shared__ int lc[1024];
    for (int i = threadIdx.x; i < R; i += blockDim.x) lc[i] = 0;
    __syncthreads();
    int stride = gridDim.x * blockDim.x;
    for (int i = blockIdx.x * blockDim.x + threadIdx.x; i < E; i += stride)
        atomicAdd(&lc[etype[i]], 1);
    __syncthreads();
    for (int i = threadIdx.x; i < R; i += blockDim.x)
        if (lc[i]) atomicAdd(&cnt[i], lc[i]);
}

// ---------------- exclusive scan (single block, R <= 1024) ----------------
__global__ void scan_kernel(const int* __restrict__ cnt, int* __restrict__ offs,
                            int* __restrict__ cursor, int R) {
    __shared__ int s[1024];
    int tid = threadIdx.x;
    s[tid] = (tid < R) ? cnt[tid] : 0;
    for (int off = 1; off < 1024; off <<= 1) {
        __syncthreads();
        int v = (tid >= off) ? s[tid - off] : 0;
        __syncthreads();
        s[tid] += v;
    }
    __syncthreads();
    if (tid < R) {
        int excl = (tid == 0) ? 0 : s[tid - 1];
        offs[tid]   = excl;
        cursor[tid] = excl;
        if (tid == R - 1) offs[R] = s[tid];
    }
}

// ------- scatter: store src/dst SLOTS (batch indices) per relation bucket -------
__global__ void scatter2_kernel(const int* __restrict__ etype, const int* __restrict__ eidx,
                                int* __restrict__ cursor,
                                int* __restrict__ slotS, int* __restrict__ slotD, int E) {
    int stride = gridDim.x * blockDim.x;
    for (int i = blockIdx.x * blockDim.x + threadIdx.x; i < E; i += stride) {
        int r = etype[i];
        int pos = atomicAdd(&cursor[r], 1);
        slotS[pos] = eidx[i];          // src batch slot
        slotD[pos] = eidx[E + i];      // dst batch slot
    }
}

// ------- compact: cmp[s][0:100) = bf16x2(emb[node_id[s]]) — 400B rows -------
__global__ void compact_kernel(const int* __restrict__ node_id,
                               const float* __restrict__ emb,
                               unsigned int* __restrict__ cmp, int NB) {
    int idx = blockIdx.x * blockDim.x + threadIdx.x;
    int total = NB * 100;
    if (idx >= total) return;
    int s = idx / 100, w = idx - s * 100;
    int nid = node_id[s];
    float2 v = *(const float2*)(emb + (long)nid * DD + 2 * w);
    cmp[idx] = (unsigned int)f2bf(v.x) | ((unsigned int)f2bf(v.y) << 16);
}

// ---------------- transpose W (rows x cols) -> WT (cols x rows) ----------------
__global__ void transpose_kernel(const float* __restrict__ W, float* __restrict__ WT,
                                 int rows, int cols) {
    int idx = blockIdx.x * blockDim.x + threadIdx.x;
    if (idx < rows * cols) {
        int j = idx / cols, d = idx % cols;
        WT[d * rows + j] = W[idx];
    }
}

// ---------------- main: per-(relation, side) mean-gather + GRU (bf16 rows) ----------------
__launch_bounds__(256)
__global__ void relgru2_kernel(const int* __restrict__ slots,        // (2,E) slot planes
                               const unsigned int* __restrict__ cmp, // (NB,100) bf16x2
                               const float* __restrict__ dyn,
                               const float* __restrict__ WT_ih,      // (D,3D)
                               const float* __restrict__ WT_hh,
                               const float* __restrict__ b_ih,
                               const float* __restrict__ b_hh,
                               const int* __restrict__ offs,
                               float* __restrict__ out,              // (R,1,D,2)
                               int E) {
    const int r    = blockIdx.x;
    const int side = blockIdx.y;
    const int tid  = threadIdx.x;
    const int w    = tid >> 6;
    const int lane = tid & 63;

    __shared__ float red[4][DD];
    __shared__ float xs[DD];
    __shared__ float hs[DD];
    __shared__ float gi[DD3];
    __shared__ float gh[DD3];

    const int beg = offs[r];
    const int end = offs[r + 1];
    const int n   = end - beg;
    const int* __restrict__ plane = slots + (long)side * E;

    // ---- phase A: wave w sums edges beg+w, beg+w+4, ... (lane<50: ushort4 = 4 dims) ----
    float a0 = 0.f, a1 = 0.f, a2 = 0.f, a3 = 0.f;
    int j = beg + w;
    for (; j + 4 < end; j += 8) {
        int sA = plane[j];
        int sB = plane[j + 4];
        if (lane < 50) {
            ushort4 va = ((const ushort4*)(cmp + (long)sA * 100))[lane];
            ushort4 vb = ((const ushort4*)(cmp + (long)sB * 100))[lane];
            a0 += bf2f(va.x) + bf2f(vb.x);
            a1 += bf2f(va.y) + bf2f(vb.y);
            a2 += bf2f(va.z) + bf2f(vb.z);
            a3 += bf2f(va.w) + bf2f(vb.w);
        }
    }
    if (j < end) {
        int sA = plane[j];
        if (lane < 50) {
            ushort4 va = ((const ushort4*)(cmp + (long)sA * 100))[lane];
            a0 += bf2f(va.x); a1 += bf2f(va.y); a2 += bf2f(va.z); a3 += bf2f(va.w);
        }
    }
    if (lane < 50) {
        float4 v4 = make_float4(a0, a1, a2, a3);
        *(float4*)&red[w][lane * 4] = v4;
    }
    __syncthreads();

    if (tid < DD) {
        float s = red[0][tid] + red[1][tid] + red[2][tid] + red[3][tid];
        xs[tid] = (n > 0) ? s / (float)n : 0.f;
        hs[tid] = dyn[((long)r * DD + tid) * 2 + side];
    }
    __syncthreads();

    // ---- phase B: two GEMVs ----
    {
        float a0g = 0.f, a1g = 0.f, a2g = 0.f;
        float c0g = 0.f, c1g = 0.f, c2g = 0.f;
        const bool has2 = (tid + 512) < DD3;   // tid < 88
        for (int k = 0; k < DD; ++k) {
            float xv = xs[k];
            float hv = hs[k];
            const float* rI = WT_ih + k * DD3;
            const float* rH = WT_hh + k * DD3;
            a0g = fmaf(xv, rI[tid], a0g);
            c0g = fmaf(hv, rH[tid], c0g);
            a1g = fmaf(xv, rI[tid + 256], a1g);
            c1g = fmaf(hv, rH[tid + 256], c1g);
            if (has2) {
                a2g = fmaf(xv, rI[tid + 512], a2g);
                c2g = fmaf(hv, rH[tid + 512], c2g);
            }
        }
        gi[tid]       = a0g + b_ih[tid];
        gh[tid]       = c0g + b_hh[tid];
        gi[tid + 256] = a1g + b_ih[tid + 256];
        gh[tid + 256] = c1g + b_hh[tid + 256];
        if (has2) {
            gi[tid + 512] = a2g + b_ih[tid + 512];
            gh[tid + 512] = c2g + b_hh[tid + 512];
        }
    }
    __syncthreads();

    // ---- phase C: GRU combine + write ----
    if (tid < DD) {
        float rr = 1.f / (1.f + __expf(-(gi[tid] + gh[tid])));
        float zz = 1.f / (1.f + __expf(-(gi[DD + tid] + gh[DD + tid])));
        float nn = tanhf(gi[2 * DD + tid] + rr * gh[2 * DD + tid]);
        float o  = (1.f - zz) * nn + zz * hs[tid];
        out[((long)r * DD + tid) * 2 + side] = o;
    }
}

// ================= fallback path (tiny ws): atomics into d_out ================
__global__ void atomic_acc_kernel(const int* __restrict__ eidx, const int* __restrict__ etype,
                                  const int* __restrict__ node_id, const float* __restrict__ emb,
                                  float* __restrict__ acc, int E) {
    int gtid = blockIdx.x * blockDim.x + threadIdx.x;
    int wave = gtid >> 6, lane = gtid & 63;
    int nwaves = (gridDim.x * blockDim.x) >> 6;
    for (int e = wave; e < E; e += nwaves) {
        int r = etype[e];
        float* dst = acc + (long)r * DD * 2;
        for (int side = 0; side < 2; ++side) {
            int nid = node_id[eidx[(long)side * E + e]];
            const float* row = emb + (long)nid * DD;
            for (int d = lane; d < DD; d += 64)
                atomicAdd(&dst[d * 2 + side], row[d]);
        }
    }
}

__launch_bounds__(256)
__global__ void gru_inplace_kernel(const float* __restrict__ dyn, const float* __restrict__ W_ih,
                                   const float* __restrict__ W_hh, const float* __restrict__ b_ih,
                                   const float* __restrict__ b_hh, const int* __restrict__ cnt,
                                   float* __restrict__ out) {
    const int r = blockIdx.x, side = blockIdx.y, tid = threadIdx.x;
    __shared__ float xs[DD], hs[DD], gi[DD3], gh[DD3];
    if (tid < DD) {
        float s = out[((long)r * DD + tid) * 2 + side];
        int n = cnt[r];
        xs[tid] = (n > 0) ? s / (float)n : 0.f;
        hs[tid] = dyn[((long)r * DD + tid) * 2 + side];
    }
    __syncthreads();
    for (int jj = tid; jj < DD3; jj += 256) {
        float a = b_ih[jj], c = b_hh[jj];
        const float* rI = W_ih + (long)jj * DD;
        const float* rH = W_hh + (long)jj * DD;
        for (int k = 0; k < DD; ++k) { a = fmaf(xs[k], rI[k], a); c = fmaf(hs[k], rH[k], c); }
        gi[jj] = a; gh[jj] = c;
    }
    __syncthreads();
    if (tid < DD) {
        float rr = 1.f / (1.f + __expf(-(gi[tid] + gh[tid])));
        float zz = 1.f / (1.f + __expf(-(gi[DD + tid] + gh[DD + tid])));
        float nn = tanhf(gi[2 * DD + tid] + rr * gh[2 * DD + tid]);
        out[((long)r * DD + tid) * 2 + side] = (1.f - zz) * nn + zz * hs[tid];
    }
}

extern "C" void kernel_launch(void* const* d_in, const int* in_sizes, int n_in,
                              void* d_out, int out_size, void* d_ws, size_t ws_size,
                              hipStream_t stream) {
    const int*   eidx    = (const int*)d_in[0];
    const int*   etype   = (const int*)d_in[1];
    const int*   node_id = (const int*)d_in[2];
    const float* emb     = (const float*)d_in[3];
    const float* dyn     = (const float*)d_in[4];
    const float* W_ih    = (const float*)d_in[5];
    const float* W_hh    = (const float*)d_in[6];
    const float* b_ih    = (const float*)d_in[7];
    const float* b_hh    = (const float*)d_in[8];
    float*       out     = (float*)d_out;

    const int E  = in_sizes[1];
    const int NB = in_sizes[2];                // 50,000
    const int D  = in_sizes[7] / 3;            // 200
    const int R  = in_sizes[4] / (2 * D);      // 1000
    const int D3 = 3 * D;                      // 600

    char* p = (char*)d_ws;
    auto take = [&](size_t bytes) { char* q = p; p += (bytes + 255) & ~(size_t)255; return q; };
    int*          cnt    = (int*)         take((size_t)R * 4);
    int*          cursor = (int*)         take((size_t)R * 4);
    int*          offs   = (int*)         take((size_t)(R + 1) * 4);
    int*          slots  = (int*)         take((size_t)2 * E * 4);      // src, dst planes
    unsigned int* cmp    = (unsigned int*)take((size_t)NB * 100 * 4);   // bf16 compact rows
    float*        WT_ih  = (float*)       take((size_t)D3 * D * 4);
    float*        WT_hh  = (float*)       take((size_t)D3 * D * 4);
    size_t need_full = (size_t)(p - (char*)d_ws);

    if (ws_size >= need_full) {
        zero_kernel<<<1, 256, 0, stream>>>(cnt, R);
        hist_kernel<<<512, 256, 0, stream>>>(etype, cnt, E, R);
        scan_kernel<<<1, 1024, 0, stream>>>(cnt, offs, cursor, R);
        scatter2_kernel<<<1024, 256, 0, stream>>>(etype, eidx, cursor, slots, slots + E, E);
        int cw = (NB * 100 + 255) / 256;
        compact_kernel<<<cw, 256, 0, stream>>>(node_id, emb, cmp, NB);
        int tw = (D3 * D + 255) / 256;
        transpose_kernel<<<tw, 256, 0, stream>>>(W_ih, WT_ih, D3, D);
        transpose_kernel<<<tw, 256, 0, stream>>>(W_hh, WT_hh, D3, D);
        dim3 grid(R, 2);
        relgru2_kernel<<<grid, 256, 0, stream>>>(slots, cmp, dyn, WT_ih, WT_hh,
                                                 b_ih, b_hh, offs, out, E);
    } else {
        zero_kernel<<<1, 256, 0, stream>>>(cnt, R);
        hist_kernel<<<512, 256, 0, stream>>>(etype, cnt, E, R);
        zerof_kernel<<<(R * D * 2 + 255) / 256, 256, 0, stream>>>(out, R * D * 2);
        atomic_acc_kernel<<<2048, 256, 0, stream>>>(eidx, etype, node_id, emb, out, E);
        dim3 grid(R, 2);
        gru_inplace_kernel<<<grid, 256, 0, stream>>>(dyn, W_ih, W_hh, b_ih, b_hh, cnt, out);
    }
}

// Round 5
// 306.217 us; speedup vs baseline: 1.7993x; 1.4765x over previous
//
#include <hip/hip_runtime.h>
#include <math.h>

// Problem constants: E=1,000,000  R=1000  D=200  N_BATCH=50,000  N_TOTAL=100,000
#define DD    200
#define DD3   600
#define G4    4          // slot groups
#define NBUKC (1000*2*G4) // 8000 buckets = R*2*G4 (runtime-checked)

typedef unsigned int  uint32;
typedef unsigned short uint16;

static __device__ inline float bf2f(uint16 u) {
    union { uint32 i; float f; } x; x.i = ((uint32)u) << 16; return x.f;
}
static __device__ inline uint16 f2bf(float f) {
    union { float f; uint32 i; } x; x.f = f;
    return (uint16)((x.i + 0x7FFFu + ((x.i >> 16) & 1u)) >> 16);
}

// ---------------- zero int counters (grid-stride) ----------------
__global__ void zero_kernel(int* __restrict__ cnt, int n) {
    int stride = gridDim.x * blockDim.x;
    for (int i = blockIdx.x * blockDim.x + threadIdx.x; i < n; i += stride) cnt[i] = 0;
}

// ---------------- zero float buffer ----------------
__global__ void zerof_kernel(float* __restrict__ p, int n) {
    int stride = gridDim.x * blockDim.x;
    for (int i = blockIdx.x * blockDim.x + threadIdx.x; i < n; i += stride) p[i] = 0.f;
}

// -------- hist over (relation, side, slot-group): 8000 bins, LDS-staged --------
__launch_bounds__(1024)
__global__ void hist4_kernel(const int* __restrict__ etype, const int* __restrict__ eidx,
                             int* __restrict__ cnt, int E, int GS, int nbuk) {
    __shared__ int lc[NBUKC];
    for (int i = threadIdx.x; i < nbuk; i += 1024) lc[i] = 0;
    __syncthreads();
    int per = (E + gridDim.x - 1) / gridDim.x;
    int beg = blockIdx.x * per;
    int end = min(E, beg + per);
    for (int e = beg + (int)threadIdx.x; e < end; e += 1024) {
        int r  = etype[e];
        int gS = eidx[e] / GS;
        int gD = eidx[E + e] / GS;
        atomicAdd(&lc[r * (2 * G4) + gS], 1);
        atomicAdd(&lc[r * (2 * G4) + G4 + gD], 1);
    }
    __syncthreads();
    for (int i = threadIdx.x; i < nbuk; i += 1024)
        if (lc[i]) atomicAdd(&cnt[i], lc[i]);
}

// ---------------- exclusive scan over nbuk (single block, chunks of 1024) ----------------
__launch_bounds__(1024)
__global__ void scan8k_kernel(const int* __restrict__ cnt, int* __restrict__ offs,
                              int* __restrict__ cursor, int n) {
    __shared__ int s[1024];
    __shared__ int carry;
    int tid = threadIdx.x;
    if (tid == 0) carry = 0;
    __syncthreads();
    for (int base = 0; base < n; base += 1024) {
        int i = base + tid;
        int v = (i < n) ? cnt[i] : 0;
        s[tid] = v;
        for (int off = 1; off < 1024; off <<= 1) {
            __syncthreads();
            int t = (tid >= off) ? s[tid - off] : 0;
            __syncthreads();
            s[tid] += t;
        }
        __syncthreads();
        int excl = carry + s[tid] - v;
        if (i < n) { offs[i] = excl; cursor[i] = excl; }
        __syncthreads();
        if (tid == 1023) carry += s[1023];
        __syncthreads();
    }
    if (tid == 0) offs[n] = carry;
}

// -------- scatter: slot (uint16) into (r, side, group) buckets --------
__global__ void scatter4_kernel(const int* __restrict__ etype, const int* __restrict__ eidx,
                                int* __restrict__ cursor, uint16* __restrict__ list,
                                int E, int GS) {
    int stride = gridDim.x * blockDim.x;
    for (int i = blockIdx.x * blockDim.x + threadIdx.x; i < E; i += stride) {
        int r  = etype[i];
        int sS = eidx[i];
        int sD = eidx[E + i];
        int pS = atomicAdd(&cursor[r * (2 * G4) + sS / GS], 1);
        list[pS] = (uint16)sS;
        int pD = atomicAdd(&cursor[r * (2 * G4) + G4 + sD / GS], 1);
        list[pD] = (uint16)sD;
    }
}

// -------- compact: cmp[h][slot][u] (u<50 uints = dims 2u,2u+1 of half h) --------
__global__ void compact2_kernel(const int* __restrict__ node_id,
                                const float* __restrict__ emb,
                                uint32* __restrict__ cmp, int NB) {
    int idx = blockIdx.x * blockDim.x + threadIdx.x;
    int total = NB * 100;
    if (idx >= total) return;
    int s = idx / 100, u = idx - s * 100;      // u in [0,100): dims 2u, 2u+1
    int nid = node_id[s];
    float2 v = *(const float2*)(emb + (long)nid * DD + 2 * u);
    int h = u / 50, u2 = u - h * 50;
    cmp[((long)h * NB + s) * 50 + u2] = (uint32)f2bf(v.x) | ((uint32)f2bf(v.y) << 16);
}

// ---------------- transpose W (rows x cols) -> WT (cols x rows) ----------------
__global__ void transpose_kernel(const float* __restrict__ W, float* __restrict__ WT,
                                 int rows, int cols) {
    int idx = blockIdx.x * blockDim.x + threadIdx.x;
    if (idx < rows * cols) {
        int j = idx / cols, d = idx % cols;
        WT[d * rows + j] = W[idx];
    }
}

// -------- partial sums: block = (rs, g, h); key = blockIdx%8 -> XCD-local slice --------
__launch_bounds__(256)
__global__ void partial4_kernel(const uint16* __restrict__ list,
                                const uint32* __restrict__ cmp,
                                const int* __restrict__ offs,
                                uint16* __restrict__ partial,   // (nbuk, 200) bf16 sums
                                int NB) {
    const int key = blockIdx.x & 7;          // XCD key (round-robin dispatch)
    const int g   = key & 3;
    const int h   = key >> 2;
    const int rs  = blockIdx.x >> 3;         // r*2+side, 0..1999
    const int b   = rs * G4 + g;
    const int tid = threadIdx.x;
    const int w   = tid >> 6;
    const int lane = tid & 63;

    __shared__ float red[4][100];

    const int beg = offs[b];
    const int end = offs[b + 1];
    const uint32* __restrict__ base = cmp + (long)h * NB * 50;

    float a0 = 0.f, a1 = 0.f;
    int j = beg + w;
    for (; j + 4 < end; j += 8) {
        int sA = list[j];
        int sB = list[j + 4];
        if (lane < 50) {
            uint32 va = base[(long)sA * 50 + lane];
            uint32 vb = base[(long)sB * 50 + lane];
            a0 += bf2f((uint16)(va & 0xFFFF)) + bf2f((uint16)(vb & 0xFFFF));
            a1 += bf2f((uint16)(va >> 16))    + bf2f((uint16)(vb >> 16));
        }
    }
    if (j < end) {
        int sA = list[j];
        if (lane < 50) {
            uint32 va = base[(long)sA * 50 + lane];
            a0 += bf2f((uint16)(va & 0xFFFF));
            a1 += bf2f((uint16)(va >> 16));
        }
    }
    if (lane < 50) {
        *(float2*)&red[w][2 * lane] = make_float2(a0, a1);
    }
    __syncthreads();

    if (tid < 100) {
        float s = red[0][tid] + red[1][tid] + red[2][tid] + red[3][tid];
        partial[(long)b * DD + h * 100 + tid] = f2bf(s);
    }
}

// -------- batched GEMV (8 relations/block) + GRU combine + write --------
__launch_bounds__(256)
__global__ void gemv_gru8_kernel(const uint16* __restrict__ partial, // (nbuk,200) bf16
                                 const float* __restrict__ dyn,      // (R,1,D,2)
                                 const float* __restrict__ WT_ih,    // (D,3D)
                                 const float* __restrict__ WT_hh,
                                 const float* __restrict__ b_ih,
                                 const float* __restrict__ b_hh,
                                 const int* __restrict__ offs,
                                 float* __restrict__ out) {          // (R,1,D,2)
    const int x    = blockIdx.x;      // relation octet
    const int side = blockIdx.y;
    const int tid  = threadIdx.x;

    __shared__ float xs[8][DD];
    __shared__ float hs[8][DD];
    __shared__ float gi[8][DD3];
    __shared__ float gh[8][DD3];

    #pragma unroll
    for (int rr = 0; rr < 8; ++rr) {
        int r = x * 8 + rr;
        int bb = (r * 2 + side) * G4;
        if (tid < DD) {
            int n = offs[bb + G4] - offs[bb];
            float s = 0.f;
            #pragma unroll
            for (int g = 0; g < G4; ++g)
                s += bf2f(partial[(long)(bb + g) * DD + tid]);
            xs[rr][tid] = (n > 0) ? s / (float)n : 0.f;
            hs[rr][tid] = dyn[((long)r * DD + tid) * 2 + side];
        }
    }
    __syncthreads();

    // GEMV: thread owns cols {tid, tid+256, tid+512(if<600)} for all 8 relations
    {
        float aI0[8], aI1[8], aI2[8], aH0[8], aH1[8], aH2[8];
        #pragma unroll
        for (int rr = 0; rr < 8; ++rr) {
            aI0[rr] = aI1[rr] = aI2[rr] = 0.f;
            aH0[rr] = aH1[rr] = aH2[rr] = 0.f;
        }
        const bool has2 = tid < (DD3 - 512);   // tid < 88
        for (int k = 0; k < DD; ++k) {
            const float* rI = WT_ih + k * DD3;
            const float* rH = WT_hh + k * DD3;
            float wi0 = rI[tid], wi1 = rI[tid + 256];
            float wh0 = rH[tid], wh1 = rH[tid + 256];
            float wi2 = has2 ? rI[tid + 512] : 0.f;
            float wh2 = has2 ? rH[tid + 512] : 0.f;
            #pragma unroll
            for (int rr = 0; rr < 8; ++rr) {
                float xv = xs[rr][k];
                float hv = hs[rr][k];
                aI0[rr] = fmaf(xv, wi0, aI0[rr]);
                aI1[rr] = fmaf(xv, wi1, aI1[rr]);
                aI2[rr] = fmaf(xv, wi2, aI2[rr]);
                aH0[rr] = fmaf(hv, wh0, aH0[rr]);
                aH1[rr] = fmaf(hv, wh1, aH1[rr]);
                aH2[rr] = fmaf(hv, wh2, aH2[rr]);
            }
        }
        #pragma unroll
        for (int rr = 0; rr < 8; ++rr) {
            gi[rr][tid]       = aI0[rr] + b_ih[tid];
            gh[rr][tid]       = aH0[rr] + b_hh[tid];
            gi[rr][tid + 256] = aI1[rr] + b_ih[tid + 256];
            gh[rr][tid + 256] = aH1[rr] + b_hh[tid + 256];
            if (has2) {
                gi[rr][tid + 512] = aI2[rr] + b_ih[tid + 512];
                gh[rr][tid + 512] = aH2[rr] + b_hh[tid + 512];
            }
        }
    }
    __syncthreads();

    if (tid < DD) {
        #pragma unroll
        for (int rr = 0; rr < 8; ++rr) {
            int r = x * 8 + rr;
            float rg = 1.f / (1.f + __expf(-(gi[rr][tid] + gh[rr][tid])));
            float zz = 1.f / (1.f + __expf(-(gi[rr][DD + tid] + gh[rr][DD + tid])));
            float nn = tanhf(gi[rr][2 * DD + tid] + rg * gh[rr][2 * DD + tid]);
            out[((long)r * DD + tid) * 2 + side] = (1.f - zz) * nn + zz * hs[rr][tid];
        }
    }
}

// ================= fallback path (tiny ws): atomics into d_out ================
__global__ void hist_kernel(const int* __restrict__ etype, int* __restrict__ cnt,
                            int E, int R) {
    __shared__ int lc[1024];
    for (int i = threadIdx.x; i < R; i += blockDim.x) lc[i] = 0;
    __syncthreads();
    int stride = gridDim.x * blockDim.x;
    for (int i = blockIdx.x * blockDim.x + threadIdx.x; i < E; i += stride)
        atomicAdd(&lc[etype[i]], 1);
    __syncthreads();
    for (int i = threadIdx.x; i < R; i += blockDim.x)
        if (lc[i]) atomicAdd(&cnt[i], lc[i]);
}

__global__ void atomic_acc_kernel(const int* __restrict__ eidx, const int* __restrict__ etype,
                                  const int* __restrict__ node_id, const float* __restrict__ emb,
                                  float* __restrict__ acc, int E) {
    int gtid = blockIdx.x * blockDim.x + threadIdx.x;
    int wave = gtid >> 6, lane = gtid & 63;
    int nwaves = (gridDim.x * blockDim.x) >> 6;
    for (int e = wave; e < E; e += nwaves) {
        int r = etype[e];
        float* dst = acc + (long)r * DD * 2;
        for (int side = 0; side < 2; ++side) {
            int nid = node_id[eidx[(long)side * E + e]];
            const float* row = emb + (long)nid * DD;
            for (int d = lane; d < DD; d += 64)
                atomicAdd(&dst[d * 2 + side], row[d]);
        }
    }
}

__launch_bounds__(256)
__global__ void gru_inplace_kernel(const float* __restrict__ dyn, const float* __restrict__ W_ih,
                                   const float* __restrict__ W_hh, const float* __restrict__ b_ih,
                                   const float* __restrict__ b_hh, const int* __restrict__ cnt,
                                   float* __restrict__ out) {
    const int r = blockIdx.x, side = blockIdx.y, tid = threadIdx.x;
    __shared__ float xs[DD], hs[DD], gi[DD3], gh[DD3];
    if (tid < DD) {
        float s = out[((long)r * DD + tid) * 2 + side];
        int n = cnt[r];
        xs[tid] = (n > 0) ? s / (float)n : 0.f;
        hs[tid] = dyn[((long)r * DD + tid) * 2 + side];
    }
    __syncthreads();
    for (int jj = tid; jj < DD3; jj += 256) {
        float a = b_ih[jj], c = b_hh[jj];
        const float* rI = W_ih + (long)jj * DD;
        const float* rH = W_hh + (long)jj * DD;
        for (int k = 0; k < DD; ++k) { a = fmaf(xs[k], rI[k], a); c = fmaf(hs[k], rH[k], c); }
        gi[jj] = a; gh[jj] = c;
    }
    __syncthreads();
    if (tid < DD) {
        float rr = 1.f / (1.f + __expf(-(gi[tid] + gh[tid])));
        float zz = 1.f / (1.f + __expf(-(gi[DD + tid] + gh[DD + tid])));
        float nn = tanhf(gi[2 * DD + tid] + rr * gh[2 * DD + tid]);
        out[((long)r * DD + tid) * 2 + side] = (1.f - zz) * nn + zz * hs[tid];
    }
}

extern "C" void kernel_launch(void* const* d_in, const int* in_sizes, int n_in,
                              void* d_out, int out_size, void* d_ws, size_t ws_size,
                              hipStream_t stream) {
    const int*   eidx    = (const int*)d_in[0];
    const int*   etype   = (const int*)d_in[1];
    const int*   node_id = (const int*)d_in[2];
    const float* emb     = (const float*)d_in[3];
    const float* dyn     = (const float*)d_in[4];
    const float* W_ih    = (const float*)d_in[5];
    const float* W_hh    = (const float*)d_in[6];
    const float* b_ih    = (const float*)d_in[7];
    const float* b_hh    = (const float*)d_in[8];
    float*       out     = (float*)d_out;

    const int E  = in_sizes[1];
    const int NB = in_sizes[2];                // 50,000
    const int D  = in_sizes[7] / 3;            // 200
    const int R  = in_sizes[4] / (2 * D);      // 1000
    const int D3 = 3 * D;                      // 600
    const int GS = (NB + G4 - 1) / G4;         // 12,500
    const int nbuk = R * 2 * G4;               // 8000

    char* p = (char*)d_ws;
    auto take = [&](size_t bytes) { char* q = p; p += (bytes + 255) & ~(size_t)255; return q; };
    int*    cnt     = (int*)   take((size_t)nbuk * 4);
    int*    cursor  = (int*)   take((size_t)nbuk * 4);
    int*    offs    = (int*)   take((size_t)(nbuk + 1) * 4);
    uint16* list    = (uint16*)take((size_t)2 * E * 2);          // 4 MB
    uint32* cmp     = (uint32*)take((size_t)2 * NB * 50 * 4);    // 20 MB
    uint16* partial = (uint16*)take((size_t)nbuk * D * 2);       // 3.2 MB
    size_t need_base = (size_t)(p - (char*)d_ws);
    float* WT_ih;
    float* WT_hh;
    size_t wt_bytes = ((size_t)D3 * D * 4 + 255) & ~(size_t)255;
    if (ws_size >= need_base + 2 * wt_bytes) {
        WT_ih = (float*)take(wt_bytes);
        WT_hh = (float*)take(wt_bytes);
    } else {
        // overlay onto list region (dead after partial4; transposes launch after it)
        WT_ih = (float*)list;
        WT_hh = (float*)((char*)list + wt_bytes);
    }

    const bool fits = (ws_size >= need_base) && (NB <= 65535) && (R == 1000) &&
                      (D == 200) && (nbuk == NBUKC) && ((R & 7) == 0);
    if (fits) {
        zero_kernel<<<32, 256, 0, stream>>>(cnt, nbuk);
        hist4_kernel<<<64, 1024, 0, stream>>>(etype, eidx, cnt, E, GS, nbuk);
        scan8k_kernel<<<1, 1024, 0, stream>>>(cnt, offs, cursor, nbuk);
        scatter4_kernel<<<1024, 256, 0, stream>>>(etype, eidx, cursor, list, E, GS);
        int cw = (NB * 100 + 255) / 256;
        compact2_kernel<<<cw, 256, 0, stream>>>(node_id, emb, cmp, NB);
        partial4_kernel<<<nbuk * 2, 256, 0, stream>>>(list, cmp, offs, partial, NB);
        int tw = (D3 * D + 255) / 256;
        transpose_kernel<<<tw, 256, 0, stream>>>(W_ih, WT_ih, D3, D);
        transpose_kernel<<<tw, 256, 0, stream>>>(W_hh, WT_hh, D3, D);
        dim3 grid(R / 8, 2);
        gemv_gru8_kernel<<<grid, 256, 0, stream>>>(partial, dyn, WT_ih, WT_hh,
                                                   b_ih, b_hh, offs, out);
    } else {
        zero_kernel<<<32, 256, 0, stream>>>(cnt, R);
        hist_kernel<<<512, 256, 0, stream>>>(etype, cnt, E, R);
        zerof_kernel<<<(R * D * 2 + 255) / 256, 256, 0, stream>>>(out, R * D * 2);
        atomic_acc_kernel<<<2048, 256, 0, stream>>>(eidx, etype, node_id, emb, out, E);
        dim3 grid(R, 2);
        gru_inplace_kernel<<<grid, 256, 0, stream>>>(dyn, W_ih, W_hh, b_ih, b_hh, cnt, out);
    }
}

// Round 6
// 273.561 us; speedup vs baseline: 2.0141x; 1.1194x over previous
//
#include <hip/hip_runtime.h>
#include <math.h>

// Problem constants: E=1,000,000  R=1000  D=200  N_BATCH=50,000  N_TOTAL=100,000
#define DD    200
#define DD3   600
#define G4    4            // slot groups
#define NBUKC (1000*2*G4)  // 8000 buckets = R*2*G4 (runtime-checked)

typedef unsigned int   uint32;
typedef unsigned short uint16;

static __device__ inline float bf2f(uint16 u) {
    union { uint32 i; float f; } x; x.i = ((uint32)u) << 16; return x.f;
}
static __device__ inline uint16 f2bf(float f) {
    union { float f; uint32 i; } x; x.f = f;
    return (uint16)((x.i + 0x7FFFu + ((x.i >> 16) & 1u)) >> 16);
}
static __device__ inline float asf(uint32 u) {
    union { uint32 i; float f; } x; x.i = u; return x.f;
}
static __device__ inline uint32 packbf(float a, float b) {
    return (uint32)f2bf(a) | ((uint32)f2bf(b) << 16);
}

// ---------------- zero int counters (grid-stride) ----------------
__global__ void zero_kernel(int* __restrict__ cnt, int n) {
    int stride = gridDim.x * blockDim.x;
    for (int i = blockIdx.x * blockDim.x + threadIdx.x; i < n; i += stride) cnt[i] = 0;
}

// ---------------- zero float buffer ----------------
__global__ void zerof_kernel(float* __restrict__ p, int n) {
    int stride = gridDim.x * blockDim.x;
    for (int i = blockIdx.x * blockDim.x + threadIdx.x; i < n; i += stride) p[i] = 0.f;
}

// -------- hist over (relation, side, slot-group): 8000 bins, LDS-staged --------
__launch_bounds__(1024)
__global__ void hist4_kernel(const int* __restrict__ etype, const int* __restrict__ eidx,
                             int* __restrict__ cnt, int E, int GS, int nbuk) {
    __shared__ int lc[NBUKC];
    for (int i = threadIdx.x; i < nbuk; i += 1024) lc[i] = 0;
    __syncthreads();
    int per = (E + gridDim.x - 1) / gridDim.x;
    int beg = blockIdx.x * per;
    int end = min(E, beg + per);
    for (int e = beg + (int)threadIdx.x; e < end; e += 1024) {
        int r  = etype[e];
        int gS = eidx[e] / GS;
        int gD = eidx[E + e] / GS;
        atomicAdd(&lc[r * (2 * G4) + gS], 1);
        atomicAdd(&lc[r * (2 * G4) + G4 + gD], 1);
    }
    __syncthreads();
    for (int i = threadIdx.x; i < nbuk; i += 1024)
        if (lc[i]) atomicAdd(&cnt[i], lc[i]);
}

// ---------------- exclusive scan over nbuk (single block, chunks of 1024) ----------------
__launch_bounds__(1024)
__global__ void scan8k_kernel(const int* __restrict__ cnt, int* __restrict__ offs,
                              int* __restrict__ cursor, int n) {
    __shared__ int s[1024];
    __shared__ int carry;
    int tid = threadIdx.x;
    if (tid == 0) carry = 0;
    __syncthreads();
    for (int base = 0; base < n; base += 1024) {
        int i = base + tid;
        int v = (i < n) ? cnt[i] : 0;
        s[tid] = v;
        for (int off = 1; off < 1024; off <<= 1) {
            __syncthreads();
            int t = (tid >= off) ? s[tid - off] : 0;
            __syncthreads();
            s[tid] += t;
        }
        __syncthreads();
        int excl = carry + s[tid] - v;
        if (i < n) { offs[i] = excl; cursor[i] = excl; }
        __syncthreads();
        if (tid == 1023) carry += s[1023];
        __syncthreads();
    }
    if (tid == 0) offs[n] = carry;
}

// -------- scatter: slot (uint16) into (r, side, group) buckets --------
__global__ void scatter4_kernel(const int* __restrict__ etype, const int* __restrict__ eidx,
                                int* __restrict__ cursor, uint16* __restrict__ list,
                                int E, int GS) {
    int stride = gridDim.x * blockDim.x;
    for (int i = blockIdx.x * blockDim.x + threadIdx.x; i < E; i += stride) {
        int r  = etype[i];
        int sS = eidx[i];
        int sD = eidx[E + i];
        int pS = atomicAdd(&cursor[r * (2 * G4) + sS / GS], 1);
        list[pS] = (uint16)sS;
        int pD = atomicAdd(&cursor[r * (2 * G4) + G4 + sD / GS], 1);
        list[pD] = (uint16)sD;
    }
}

// -------- compact: cmp[h][slot][u2] (u2<50 uint32 = dim pair) — float4 reads --------
__global__ void compact2_kernel(const int* __restrict__ node_id,
                                const float* __restrict__ emb,
                                uint32* __restrict__ cmp, int NB) {
    int idx = blockIdx.x * blockDim.x + threadIdx.x;
    if (idx >= NB * 50) return;
    int s = idx / 50, t = idx - s * 50;        // t in [0,50): dims 4t..4t+3
    int nid = node_id[s];
    float4 v = *(const float4*)(emb + (size_t)nid * DD + 4 * t);
    int u = 2 * t;                             // uint32 index in [0,100)
    int h = (u >= 50) ? 1 : 0;
    uint32* dst = cmp + ((size_t)h * NB + s) * 50 + (u - h * 50);
    *(uint2*)dst = make_uint2(packbf(v.x, v.y), packbf(v.z, v.w));
}

// ---------------- fused transpose of both W (rows x cols) -> WT (cols x rows) ----------------
__global__ void transpose2_kernel(const float* __restrict__ A, const float* __restrict__ B,
                                  float* __restrict__ TA, float* __restrict__ TB,
                                  int rows, int cols) {
    int idx = blockIdx.x * blockDim.x + threadIdx.x;
    int n = rows * cols;
    if (idx < n) {
        int j = idx / cols, d = idx % cols;
        TA[d * rows + j] = A[idx];
    } else if (idx < 2 * n) {
        int k = idx - n;
        int j = k / cols, d = k % cols;
        TB[d * rows + j] = B[k];
    }
}

// -------- partial sums: block = (rs, g, h); key = blockIdx%8 -> XCD-local 2.5MB slice --------
// Optimized: scalar slot via readfirstlane, 2-bitop bf16 cvt, 4-deep unroll.
__launch_bounds__(256)
__global__ void partial5_kernel(const uint16* __restrict__ list,
                                const uint32* __restrict__ cmp,
                                const int* __restrict__ offs,
                                uint16* __restrict__ partial,   // (nbuk, 200) bf16 sums
                                int NB) {
    const int key  = blockIdx.x & 7;          // XCD key (round-robin dispatch)
    const int g    = key & 3;
    const int h    = key >> 2;
    const int rs   = blockIdx.x >> 3;         // r*2+side, 0..1999
    const int b    = rs * G4 + g;
    const int tid  = threadIdx.x;
    const int w    = tid >> 6;
    const int lane = tid & 63;

    __shared__ float red[4][100];

    const int beg = offs[b];
    const int end = offs[b + 1];
    const uint32* __restrict__ cmpH = cmp + (size_t)h * NB * 50;

    float a0 = 0.f, a1 = 0.f;
    if (lane < 50) {
        int j = beg + w;
        for (; j + 12 < end; j += 16) {
            int s0 = __builtin_amdgcn_readfirstlane((int)list[j]);
            int s1 = __builtin_amdgcn_readfirstlane((int)list[j + 4]);
            int s2 = __builtin_amdgcn_readfirstlane((int)list[j + 8]);
            int s3 = __builtin_amdgcn_readfirstlane((int)list[j + 12]);
            uint32 v0 = cmpH[s0 * 50 + lane];
            uint32 v1 = cmpH[s1 * 50 + lane];
            uint32 v2 = cmpH[s2 * 50 + lane];
            uint32 v3 = cmpH[s3 * 50 + lane];
            a0 += (asf(v0 << 16) + asf(v1 << 16)) + (asf(v2 << 16) + asf(v3 << 16));
            a1 += (asf(v0 & 0xFFFF0000u) + asf(v1 & 0xFFFF0000u))
                + (asf(v2 & 0xFFFF0000u) + asf(v3 & 0xFFFF0000u));
        }
        for (; j < end; j += 4) {
            int s0 = __builtin_amdgcn_readfirstlane((int)list[j]);
            uint32 v0 = cmpH[s0 * 50 + lane];
            a0 += asf(v0 << 16);
            a1 += asf(v0 & 0xFFFF0000u);
        }
        *(float2*)&red[w][2 * lane] = make_float2(a0, a1);
    }
    __syncthreads();

    if (tid < 100) {
        float s = red[0][tid] + red[1][tid] + red[2][tid] + red[3][tid];
        partial[(size_t)b * DD + h * 100 + tid] = f2bf(s);
    }
}

// -------- batched GEMV (8 relations/block) + GRU combine + write --------
__launch_bounds__(256)
__global__ void gemv_gru8_kernel(const uint16* __restrict__ partial, // (nbuk,200) bf16
                                 const float* __restrict__ dyn,      // (R,1,D,2)
                                 const float* __restrict__ WT_ih,    // (D,3D)
                                 const float* __restrict__ WT_hh,
                                 const float* __restrict__ b_ih,
                                 const float* __restrict__ b_hh,
                                 const int* __restrict__ offs,
                                 float* __restrict__ out) {          // (R,1,D,2)
    const int x    = blockIdx.x;      // relation octet
    const int side = blockIdx.y;
    const int tid  = threadIdx.x;

    __shared__ float xs[8][DD];
    __shared__ float hs[8][DD];
    __shared__ float gi[8][DD3];
    __shared__ float gh[8][DD3];

    #pragma unroll
    for (int rr = 0; rr < 8; ++rr) {
        int r = x * 8 + rr;
        int bb = (r * 2 + side) * G4;
        if (tid < DD) {
            int n = offs[bb + G4] - offs[bb];
            float s = 0.f;
            #pragma unroll
            for (int g = 0; g < G4; ++g)
                s += bf2f(partial[(size_t)(bb + g) * DD + tid]);
            xs[rr][tid] = (n > 0) ? s / (float)n : 0.f;
            hs[rr][tid] = dyn[((size_t)r * DD + tid) * 2 + side];
        }
    }
    __syncthreads();

    {
        float aI0[8], aI1[8], aI2[8], aH0[8], aH1[8], aH2[8];
        #pragma unroll
        for (int rr = 0; rr < 8; ++rr) {
            aI0[rr] = aI1[rr] = aI2[rr] = 0.f;
            aH0[rr] = aH1[rr] = aH2[rr] = 0.f;
        }
        const bool has2 = tid < (DD3 - 512);   // tid < 88
        for (int k = 0; k < DD; ++k) {
            const float* rI = WT_ih + k * DD3;
            const float* rH = WT_hh + k * DD3;
            float wi0 = rI[tid], wi1 = rI[tid + 256];
            float wh0 = rH[tid], wh1 = rH[tid + 256];
            float wi2 = has2 ? rI[tid + 512] : 0.f;
            float wh2 = has2 ? rH[tid + 512] : 0.f;
            #pragma unroll
            for (int rr = 0; rr < 8; ++rr) {
                float xv = xs[rr][k];
                float hv = hs[rr][k];
                aI0[rr] = fmaf(xv, wi0, aI0[rr]);
                aI1[rr] = fmaf(xv, wi1, aI1[rr]);
                aI2[rr] = fmaf(xv, wi2, aI2[rr]);
                aH0[rr] = fmaf(hv, wh0, aH0[rr]);
                aH1[rr] = fmaf(hv, wh1, aH1[rr]);
                aH2[rr] = fmaf(hv, wh2, aH2[rr]);
            }
        }
        #pragma unroll
        for (int rr = 0; rr < 8; ++rr) {
            gi[rr][tid]       = aI0[rr] + b_ih[tid];
            gh[rr][tid]       = aH0[rr] + b_hh[tid];
            gi[rr][tid + 256] = aI1[rr] + b_ih[tid + 256];
            gh[rr][tid + 256] = aH1[rr] + b_hh[tid + 256];
            if (has2) {
                gi[rr][tid + 512] = aI2[rr] + b_ih[tid + 512];
                gh[rr][tid + 512] = aH2[rr] + b_hh[tid + 512];
            }
        }
    }
    __syncthreads();

    if (tid < DD) {
        #pragma unroll
        for (int rr = 0; rr < 8; ++rr) {
            int r = x * 8 + rr;
            float rg = 1.f / (1.f + __expf(-(gi[rr][tid] + gh[rr][tid])));
            float zz = 1.f / (1.f + __expf(-(gi[rr][DD + tid] + gh[rr][DD + tid])));
            float nn = tanhf(gi[rr][2 * DD + tid] + rg * gh[rr][2 * DD + tid]);
            out[((size_t)r * DD + tid) * 2 + side] = (1.f - zz) * nn + zz * hs[rr][tid];
        }
    }
}

// ================= fallback path (tiny ws): atomics into d_out ================
__global__ void hist_kernel(const int* __restrict__ etype, int* __restrict__ cnt,
                            int E, int R) {
    __shared__ int lc[1024];
    for (int i = threadIdx.x; i < R; i += blockDim.x) lc[i] = 0;
    __syncthreads();
    int stride = gridDim.x * blockDim.x;
    for (int i = blockIdx.x * blockDim.x + threadIdx.x; i < E; i += stride)
        atomicAdd(&lc[etype[i]], 1);
    __syncthreads();
    for (int i = threadIdx.x; i < R; i += blockDim.x)
        if (lc[i]) atomicAdd(&cnt[i], lc[i]);
}

__global__ void atomic_acc_kernel(const int* __restrict__ eidx, const int* __restrict__ etype,
                                  const int* __restrict__ node_id, const float* __restrict__ emb,
                                  float* __restrict__ acc, int E) {
    int gtid = blockIdx.x * blockDim.x + threadIdx.x;
    int wave = gtid >> 6, lane = gtid & 63;
    int nwaves = (gridDim.x * blockDim.x) >> 6;
    for (int e = wave; e < E; e += nwaves) {
        int r = etype[e];
        float* dst = acc + (size_t)r * DD * 2;
        for (int side = 0; side < 2; ++side) {
            int nid = node_id[eidx[(size_t)side * E + e]];
            const float* row = emb + (size_t)nid * DD;
            for (int d = lane; d < DD; d += 64)
                atomicAdd(&dst[d * 2 + side], row[d]);
        }
    }
}

__launch_bounds__(256)
__global__ void gru_inplace_kernel(const float* __restrict__ dyn, const float* __restrict__ W_ih,
                                   const float* __restrict__ W_hh, const float* __restrict__ b_ih,
                                   const float* __restrict__ b_hh, const int* __restrict__ cnt,
                                   float* __restrict__ out) {
    const int r = blockIdx.x, side = blockIdx.y, tid = threadIdx.x;
    __shared__ float xs[DD], hs[DD], gi[DD3], gh[DD3];
    if (tid < DD) {
        float s = out[((size_t)r * DD + tid) * 2 + side];
        int n = cnt[r];
        xs[tid] = (n > 0) ? s / (float)n : 0.f;
        hs[tid] = dyn[((size_t)r * DD + tid) * 2 + side];
    }
    __syncthreads();
    for (int jj = tid; jj < DD3; jj += 256) {
        float a = b_ih[jj], c = b_hh[jj];
        const float* rI = W_ih + (size_t)jj * DD;
        const float* rH = W_hh + (size_t)jj * DD;
        for (int k = 0; k < DD; ++k) { a = fmaf(xs[k], rI[k], a); c = fmaf(hs[k], rH[k], c); }
        gi[jj] = a; gh[jj] = c;
    }
    __syncthreads();
    if (tid < DD) {
        float rr = 1.f / (1.f + __expf(-(gi[tid] + gh[tid])));
        float zz = 1.f / (1.f + __expf(-(gi[DD + tid] + gh[DD + tid])));
        float nn = tanhf(gi[2 * DD + tid] + rr * gh[2 * DD + tid]);
        out[((size_t)r * DD + tid) * 2 + side] = (1.f - zz) * nn + zz * hs[tid];
    }
}

extern "C" void kernel_launch(void* const* d_in, const int* in_sizes, int n_in,
                              void* d_out, int out_size, void* d_ws, size_t ws_size,
                              hipStream_t stream) {
    const int*   eidx    = (const int*)d_in[0];
    const int*   etype   = (const int*)d_in[1];
    const int*   node_id = (const int*)d_in[2];
    const float* emb     = (const float*)d_in[3];
    const float* dyn     = (const float*)d_in[4];
    const float* W_ih    = (const float*)d_in[5];
    const float* W_hh    = (const float*)d_in[6];
    const float* b_ih    = (const float*)d_in[7];
    const float* b_hh    = (const float*)d_in[8];
    float*       out     = (float*)d_out;

    const int E  = in_sizes[1];
    const int NB = in_sizes[2];                // 50,000
    const int D  = in_sizes[7] / 3;            // 200
    const int R  = in_sizes[4] / (2 * D);      // 1000
    const int D3 = 3 * D;                      // 600
    const int GS = (NB + G4 - 1) / G4;         // 12,500
    const int nbuk = R * 2 * G4;               // 8000

    char* p = (char*)d_ws;
    auto take = [&](size_t bytes) { char* q = p; p += (bytes + 255) & ~(size_t)255; return q; };
    int*    cnt     = (int*)   take((size_t)nbuk * 4);
    int*    cursor  = (int*)   take((size_t)nbuk * 4);
    int*    offs    = (int*)   take((size_t)(nbuk + 1) * 4);
    uint16* list    = (uint16*)take((size_t)2 * E * 2);          // 4 MB
    uint32* cmp     = (uint32*)take((size_t)2 * NB * 50 * 4);    // 20 MB
    uint16* partial = (uint16*)take((size_t)nbuk * D * 2);       // 3.2 MB
    size_t need_base = (size_t)(p - (char*)d_ws);
    float* WT_ih;
    float* WT_hh;
    size_t wt_bytes = ((size_t)D3 * D * 4 + 255) & ~(size_t)255;
    if (ws_size >= need_base + 2 * wt_bytes) {
        WT_ih = (float*)take(wt_bytes);
        WT_hh = (float*)take(wt_bytes);
    } else {
        // overlay onto list region (list is dead once partial5 finishes;
        // transpose2 launches after it)
        WT_ih = (float*)list;
        WT_hh = (float*)((char*)list + wt_bytes);
    }

    const bool fits = (ws_size >= need_base) && (NB <= 65535) && (R == 1000) &&
                      (D == 200) && (nbuk == NBUKC) && ((R & 7) == 0);
    if (fits) {
        zero_kernel<<<32, 256, 0, stream>>>(cnt, nbuk);
        hist4_kernel<<<64, 1024, 0, stream>>>(etype, eidx, cnt, E, GS, nbuk);
        scan8k_kernel<<<1, 1024, 0, stream>>>(cnt, offs, cursor, nbuk);
        scatter4_kernel<<<1024, 256, 0, stream>>>(etype, eidx, cursor, list, E, GS);
        int cw = (NB * 50 + 255) / 256;
        compact2_kernel<<<cw, 256, 0, stream>>>(node_id, emb, cmp, NB);
        partial5_kernel<<<nbuk * 2, 256, 0, stream>>>(list, cmp, offs, partial, NB);
        int tw = (2 * D3 * D + 255) / 256;
        transpose2_kernel<<<tw, 256, 0, stream>>>(W_ih, W_hh, WT_ih, WT_hh, D3, D);
        dim3 grid(R / 8, 2);
        gemv_gru8_kernel<<<grid, 256, 0, stream>>>(partial, dyn, WT_ih, WT_hh,
                                                   b_ih, b_hh, offs, out);
    } else {
        zero_kernel<<<32, 256, 0, stream>>>(cnt, R);
        hist_kernel<<<512, 256, 0, stream>>>(etype, cnt, E, R);
        zerof_kernel<<<(R * D * 2 + 255) / 256, 256, 0, stream>>>(out, R * D * 2);
        atomic_acc_kernel<<<2048, 256, 0, stream>>>(eidx, etype, node_id, emb, out, E);
        dim3 grid(R, 2);
        gru_inplace_kernel<<<grid, 256, 0, stream>>>(dyn, W_ih, W_hh, b_ih, b_hh, cnt, out);
    }
}